// Round 4
// baseline (407.334 us; speedup 1.0000x reference)
//
#include <hip/hip_runtime.h>

#define WW 1024
#define HH 1024
#define NIMG 2
#define NCH 8
#define HWSZ (HH * WW)
#define CHW (NCH * HWSZ)
#define PADC 544               // u32 cols per plane: 16 halo + 512 + 16 halo
#define PLANEB 2176            // PADC*4 bytes per plane
#define NBLK_MASK 2048
#define NBLK_MAIN 4096
// ws float layout: [0..2047] block mins, [2048..4095] block maxs,
// [4096] sum, [4097] cnt, [4098] ticket, diffArr at 4352
#define WS_SUM 4096
#define WS_CNT 4097
#define WS_TKT 4098
#define WS_DIFF 4352

typedef unsigned int uint;

__device__ __forceinline__ uint pknorm(float a, float b) {
    uint d;
    asm("v_cvt_pknorm_u16_f32 %0, %1, %2" : "=v"(d) : "v"(a), "v"(b));
    return d;
}
__device__ __forceinline__ uint sadu16(uint a, uint b, uint c) {
    uint d;
    asm("v_sad_u16 %0, %1, %2, %3" : "=v"(d) : "v"(a), "v"(b), "v"(c));
    return d;
}
__device__ __forceinline__ int swz(int g) { return g ^ ((g >> 3) & 7); }

__device__ __forceinline__ int reflect_idx(int t) {
    if (t < 0) t = -t;
    if (t > HH - 1) t = 2 * (HH - 1) - t;
    return t;
}

// Pass 1: per-pixel mask diff d = |mean_c(msO) - pan|, per-block min/max (f32 exact).
__global__ __launch_bounds__(256) void k_mask(const float* __restrict__ msO,
                                              const float* __restrict__ pan,
                                              float* __restrict__ wsF,
                                              float* __restrict__ diffArr) {
    int b = blockIdx.x;
    int gid = b * 256 + threadIdx.x;
    int base = gid * 4;
    int n = base >> 20;
    int hw = base & (HWSZ - 1);
    const float* po = msO + n * CHW + hw;
    float sx = 0.f, sy = 0.f, sz = 0.f, sw = 0.f;
#pragma unroll
    for (int c = 0; c < NCH; ++c) {
        float4 v = *(const float4*)(po + c * HWSZ);
        sx += v.x; sy += v.y; sz += v.z; sw += v.w;
    }
    float4 pv = *(const float4*)(pan + n * HWSZ + hw);
    float4 d;
    d.x = fabsf(sx * 0.125f - pv.x);
    d.y = fabsf(sy * 0.125f - pv.y);
    d.z = fabsf(sz * 0.125f - pv.z);
    d.w = fabsf(sw * 0.125f - pv.w);
    *(float4*)(diffArr + base) = d;

    float m = fminf(fminf(d.x, d.y), fminf(d.z, d.w));
    float M = fmaxf(fmaxf(d.x, d.y), fmaxf(d.z, d.w));
#pragma unroll
    for (int off = 32; off > 0; off >>= 1) {
        m = fminf(m, __shfl_down(m, off));
        M = fmaxf(M, __shfl_down(M, off));
    }
    __shared__ float sm[4], sM[4];
    int wid = threadIdx.x >> 6, lane = threadIdx.x & 63;
    if (lane == 0) { sm[wid] = m; sM[wid] = M; }
    __syncthreads();
    if (threadIdx.x == 0) {
        wsF[b] = fminf(fminf(sm[0], sm[1]), fminf(sm[2], sm[3]));
        wsF[2048 + b] = fmaxf(fmaxf(sM[0], sM[1]), fmaxf(sM[2], sM[3]));
        if (b == 0) {
            wsF[WS_SUM] = 0.f;
            wsF[WS_CNT] = 0.f;
            ((unsigned*)wsF)[WS_TKT] = 0u;
        }
    }
}

// Pass 2: 64-thread (1-wave) block = half an image row; 8 px/thread.
// Target staged in LDS as unorm16 channel-pairs (4 planes x 544 u32), XOR-swizzled
// granules. Inner: v_sad_u16 accumulate, sliding 2-granule register window over dj.
__global__ __launch_bounds__(64, 4) void k_main(const float* __restrict__ ms,
                                                const float* __restrict__ tgt,
                                                float* __restrict__ wsF,
                                                float* __restrict__ out) {
    __shared__ __align__(16) uint ldsU[4 * PADC]; // 8704 B
    const int t = threadIdx.x;        // 0..63
    const int b = blockIdx.x;
    const int xcd = b & 7;
    const int idx = b >> 3;           // 0..511
    const int hb = idx & 1;
    const int r = idx >> 1;           // 0..255
    const int n = r >> 7;
    const int h = xcd * 128 + (r & 127);
    const int cbase = hb * 512;       // image col base of this block
    const int w0 = cbase + 8 * t;     // first owned image col

    // ms fragment: 8 ch x 8 px packed as 4 chpair planes x 8 u32
    const float* msBase = ms + n * CHW + h * WW + w0;
    uint msq[4][8];
#pragma unroll
    for (int cp = 0; cp < 4; ++cp) {
        float4 a0 = *(const float4*)(msBase + (2 * cp) * HWSZ);
        float4 a1 = *(const float4*)(msBase + (2 * cp) * HWSZ + 4);
        float4 b0 = *(const float4*)(msBase + (2 * cp + 1) * HWSZ);
        float4 b1 = *(const float4*)(msBase + (2 * cp + 1) * HWSZ + 4);
        msq[cp][0] = pknorm(a0.x, b0.x); msq[cp][1] = pknorm(a0.y, b0.y);
        msq[cp][2] = pknorm(a0.z, b0.z); msq[cp][3] = pknorm(a0.w, b0.w);
        msq[cp][4] = pknorm(a1.x, b1.x); msq[cp][5] = pknorm(a1.y, b1.y);
        msq[cp][6] = pknorm(a1.z, b1.z); msq[cp][7] = pknorm(a1.w, b1.w);
    }

    // precomputed LDS byte offsets (within plane 0; add cp*PLANEB)
    int soffq[10];
#pragma unroll
    for (int q = 0; q < 10; ++q) soffq[q] = swz(2 * t + q) * 16;
    const int wA = swz(4 + 2 * t) * 16;
    const int wB = swz(5 + 2 * t) * 16;

    // halo: 2 u32 per thread; source col independent of di
    int eCp[2], eJ[2], eOff[2];
#pragma unroll
    for (int e = 0; e < 2; ++e) {
        int id = 2 * t + e;           // 0..127
        eCp[e] = id >> 5;             // plane
        int k = id & 31;
        int pc = (k < 16) ? k : (512 + k);   // padded col 0..15 or 528..543
        int j = cbase + pc - 16;             // image col
        if (j < 0) j = -j;
        if (j > WW - 1) j = 2 * (WW - 1) - j;
        eJ[e] = j;
        eOff[e] = eCp[e] * PLANEB + swz(pc >> 2) * 16 + (pc & 3) * 4;
    }

    uint minv[8];
#pragma unroll
    for (int p = 0; p < 8; ++p) minv[p] = 0xffffffffu;

    const float* tgtN = tgt + n * CHW;

    for (int di = 0; di < 9; ++di) {
        int gr = reflect_idx(h + (di - 4) * 4);
        __syncthreads(); // 1-wave block: cheap (waitcnt + immediate barrier)
        const float* rb = tgtN + gr * WW + w0;
#pragma unroll
        for (int cp = 0; cp < 4; ++cp) {
            float4 a0 = *(const float4*)(rb + (2 * cp) * HWSZ);
            float4 a1 = *(const float4*)(rb + (2 * cp) * HWSZ + 4);
            float4 b0 = *(const float4*)(rb + (2 * cp + 1) * HWSZ);
            float4 b1 = *(const float4*)(rb + (2 * cp + 1) * HWSZ + 4);
            uint4 u0, u1;
            u0.x = pknorm(a0.x, b0.x); u0.y = pknorm(a0.y, b0.y);
            u0.z = pknorm(a0.z, b0.z); u0.w = pknorm(a0.w, b0.w);
            u1.x = pknorm(a1.x, b1.x); u1.y = pknorm(a1.y, b1.y);
            u1.z = pknorm(a1.z, b1.z); u1.w = pknorm(a1.w, b1.w);
            *(uint4*)((char*)ldsU + cp * PLANEB + wA) = u0;
            *(uint4*)((char*)ldsU + cp * PLANEB + wB) = u1;
        }
#pragma unroll
        for (int e = 0; e < 2; ++e) {
            const float* p0 = tgtN + (2 * eCp[e]) * HWSZ + gr * WW + eJ[e];
            *(uint*)((char*)ldsU + eOff[e]) = pknorm(p0[0], p0[HWSZ]);
        }
        __syncthreads();

        // sliding window: granules 2t+dj (slot dj&1), 2t+dj+1 (slot (dj+1)&1)
        uint4 win[4][2];
#pragma unroll
        for (int cp = 0; cp < 4; ++cp) {
            win[cp][0] = *(const uint4*)((char*)ldsU + cp * PLANEB + soffq[0]);
            win[cp][1] = *(const uint4*)((char*)ldsU + cp * PLANEB + soffq[1]);
        }
#pragma unroll
        for (int dj = 0; dj < 9; ++dj) {
            if (dj) {
#pragma unroll
                for (int cp = 0; cp < 4; ++cp)
                    win[cp][(dj + 1) & 1] =
                        *(const uint4*)((char*)ldsU + cp * PLANEB + soffq[dj + 1]);
            }
            uint acc[8] = {0, 0, 0, 0, 0, 0, 0, 0};
#pragma unroll
            for (int cp = 0; cp < 4; ++cp) {
                uint4 lo = win[cp][dj & 1];
                uint4 hi = win[cp][(dj + 1) & 1];
                acc[0] = sadu16(msq[cp][0], lo.x, acc[0]);
                acc[1] = sadu16(msq[cp][1], lo.y, acc[1]);
                acc[2] = sadu16(msq[cp][2], lo.z, acc[2]);
                acc[3] = sadu16(msq[cp][3], lo.w, acc[3]);
                acc[4] = sadu16(msq[cp][4], hi.x, acc[4]);
                acc[5] = sadu16(msq[cp][5], hi.y, acc[5]);
                acc[6] = sadu16(msq[cp][6], hi.z, acc[6]);
                acc[7] = sadu16(msq[cp][7], hi.w, acc[7]);
            }
#pragma unroll
            for (int p = 0; p < 8; ++p) minv[p] = min(minv[p], acc[p]);
        }
    }

    // ---- epilogue (single wave, no LDS needed) ----
    float lmin = 1.0e38f, lmax = -1.0e38f;
#pragma unroll
    for (int k = 0; k < 8; ++k) {
        float4 v = ((const float4*)wsF)[k * 64 + t];
        float4 w = ((const float4*)(wsF + 2048))[k * 64 + t];
        lmin = fminf(lmin, fminf(fminf(v.x, v.y), fminf(v.z, v.w)));
        lmax = fmaxf(lmax, fmaxf(fmaxf(w.x, w.y), fmaxf(w.z, w.w)));
    }
#pragma unroll
    for (int off = 32; off > 0; off >>= 1) {
        lmin = fminf(lmin, __shfl_xor(lmin, off));
        lmax = fmaxf(lmax, __shfl_xor(lmax, off));
    }
    float thresh = lmin + (lmax - lmin) * (10.0f / 255.0f);

    const float* dp = wsF + WS_DIFF + n * HWSZ + h * WW + w0;
    float4 da = *(const float4*)dp;
    float4 db = *(const float4*)(dp + 4);
    float dv[8] = {da.x, da.y, da.z, da.w, db.x, db.y, db.z, db.w};

    const float inv = 1.0f / 65535.0f;
    float lsum = 0.f, lcnt = 0.f;
#pragma unroll
    for (int p = 0; p < 8; ++p) {
        if (dv[p] > thresh) { lsum += (float)minv[p] * inv; lcnt += 1.f; }
    }
#pragma unroll
    for (int off = 32; off > 0; off >>= 1) {
        lsum += __shfl_down(lsum, off);
        lcnt += __shfl_down(lcnt, off);
    }
    if (t == 0) {
        atomicAdd(&wsF[WS_SUM], lsum);
        atomicAdd(&wsF[WS_CNT], lcnt);
        __threadfence();
        unsigned tk = atomicAdd((unsigned*)&wsF[WS_TKT], 1u);
        if (tk == NBLK_MAIN - 1) {
            float s = atomicAdd(&wsF[WS_SUM], 0.f);
            float c = atomicAdd(&wsF[WS_CNT], 0.f);
            out[0] = (c > 0.f) ? (s / fmaxf(c, 1.f)) : 0.f;
        }
    }
}

extern "C" void kernel_launch(void* const* d_in, const int* in_sizes, int n_in,
                              void* d_out, int out_size, void* d_ws, size_t ws_size,
                              hipStream_t stream) {
    const float* ms  = (const float*)d_in[0];
    const float* tgt = (const float*)d_in[1];
    const float* msO = (const float*)d_in[2];
    const float* pan = (const float*)d_in[3];
    float* out = (float*)d_out;
    float* wsF = (float*)d_ws;

    k_mask<<<NBLK_MASK, 256, 0, stream>>>(msO, pan, wsF, wsF + WS_DIFF);
    k_main<<<NBLK_MAIN, 64, 0, stream>>>(ms, tgt, wsF, out);
}

// Round 5
// 375.906 us; speedup vs baseline: 1.0836x; 1.0836x over previous
//
#include <hip/hip_runtime.h>

#define WW 1024
#define HH 1024
#define NIMG 2
#define NCH 8
#define HWSZ (HH * WW)
#define CHW (NCH * HWSZ)
#define NBLK_MASK 2048
#define NBLK_MAIN 4096
// ws u32/float layout: [0..2047] block mins, [2048..4095] block maxs,
// [4096] sum, [4097] cnt, [4098] ticket, diff at 4352 (2M floats),
// quantized target at WS_QT (8M u32 = 32MB)
#define WS_SUM 4096
#define WS_CNT 4097
#define WS_TKT 4098
#define WS_DIFF 4352
#define WS_QT (4352 + 2 * HWSZ)

typedef unsigned int uint;

__device__ __forceinline__ uint pknorm(float a, float b) {
    uint d;
    asm("v_cvt_pknorm_u16_f32 %0, %1, %2" : "=v"(d) : "v"(a), "v"(b));
    return d;
}
__device__ __forceinline__ uint sadu16(uint a, uint b, uint c) {
    uint d;
    asm("v_sad_u16 %0, %1, %2, %3" : "=v"(d) : "v"(a), "v"(b), "v"(c));
    return d;
}
__device__ __forceinline__ int reflect_idx(int t) {
    if (t < 0) t = -t;
    if (t > HH - 1) t = 2 * (HH - 1) - t;
    return t;
}

#define GLD16(g, l)                                                         \
    __builtin_amdgcn_global_load_lds(                                       \
        (const __attribute__((address_space(1))) uint*)(g),                 \
        (__attribute__((address_space(3))) uint*)(l), 16, 0, 0)

// Pass 0: quantize tgt to unorm16 chpair u32, granule-deinterleaved rows.
// qt[(n*4+cp)*1024 + row][1024 u32]: slots 0..127 = even granules, 128..255 = odd.
__global__ __launch_bounds__(256) void k_quant(const float* __restrict__ tgt,
                                               uint* __restrict__ qt) {
    int b = blockIdx.x;            // (n*4+cp)*1024 + row
    int t = threadIdx.x;           // granule 0..255
    int row = b & 1023;
    int pcp = b >> 10;             // n*4+cp
    int n = pcp >> 2, cp = pcp & 3;
    const float* base = tgt + (size_t)(n * NCH + 2 * cp) * HWSZ + row * WW + 4 * t;
    float4 a = *(const float4*)base;
    float4 c = *(const float4*)(base + HWSZ);
    uint4 u;
    u.x = pknorm(a.x, c.x); u.y = pknorm(a.y, c.y);
    u.z = pknorm(a.z, c.z); u.w = pknorm(a.w, c.w);
    int slot = (t & 1) ? (128 + (t >> 1)) : (t >> 1);
    *(uint4*)(qt + (size_t)b * 1024 + slot * 4) = u;
}

// Pass 1: per-pixel mask diff d = |mean_c(msO) - pan|, per-block min/max (f32 exact).
__global__ __launch_bounds__(256) void k_mask(const float* __restrict__ msO,
                                              const float* __restrict__ pan,
                                              float* __restrict__ wsF,
                                              float* __restrict__ diffArr) {
    int b = blockIdx.x;
    int gid = b * 256 + threadIdx.x;
    int base = gid * 4;
    int n = base >> 20;
    int hw = base & (HWSZ - 1);
    const float* po = msO + n * CHW + hw;
    float sx = 0.f, sy = 0.f, sz = 0.f, sw = 0.f;
#pragma unroll
    for (int c = 0; c < NCH; ++c) {
        float4 v = *(const float4*)(po + c * HWSZ);
        sx += v.x; sy += v.y; sz += v.z; sw += v.w;
    }
    float4 pv = *(const float4*)(pan + n * HWSZ + hw);
    float4 d;
    d.x = fabsf(sx * 0.125f - pv.x);
    d.y = fabsf(sy * 0.125f - pv.y);
    d.z = fabsf(sz * 0.125f - pv.z);
    d.w = fabsf(sw * 0.125f - pv.w);
    *(float4*)(diffArr + base) = d;

    float m = fminf(fminf(d.x, d.y), fminf(d.z, d.w));
    float M = fmaxf(fmaxf(d.x, d.y), fmaxf(d.z, d.w));
#pragma unroll
    for (int off = 32; off > 0; off >>= 1) {
        m = fminf(m, __shfl_down(m, off));
        M = fmaxf(M, __shfl_down(M, off));
    }
    __shared__ float sm[4], sM[4];
    int wid = threadIdx.x >> 6, lane = threadIdx.x & 63;
    if (lane == 0) { sm[wid] = m; sM[wid] = M; }
    __syncthreads();
    if (threadIdx.x == 0) {
        wsF[b] = fminf(fminf(sm[0], sm[1]), fminf(sm[2], sm[3]));
        wsF[2048 + b] = fmaxf(fmaxf(sM[0], sM[1]), fmaxf(sM[2], sM[3]));
        if (b == 0) {
            wsF[WS_SUM] = 0.f;
            wsF[WS_CNT] = 0.f;
            ((unsigned*)wsF)[WS_TKT] = 0u;
        }
    }
}

// Pass 2: 1-wave block = half row, 8 px/lane. Double-buffered async DMA staging of
// pre-quantized rows (USE_QT) or synchronous f32+pknorm staging (fallback).
// Local plane = 544 u32 (16 halo | 512 | 16 halo), deinterleaved:
// old granule go -> slot (go even ? go/2 : 68+go/2). Lane reads stride-1 slots.
template <bool USE_QT>
__global__ __launch_bounds__(64, 4) void k_main(const float* __restrict__ ms,
                                                const float* __restrict__ tgt,
                                                const uint* __restrict__ qt,
                                                float* __restrict__ wsF,
                                                float* __restrict__ out) {
    __shared__ __align__(16) uint ldsU[2][4 * 544]; // 17408 B
    const int t = threadIdx.x;        // 0..63
    const int b = blockIdx.x;
    const int xcd = b & 7;
    const int idx = b >> 3;           // 0..511
    const int hb = idx & 1;
    const int r = idx >> 1;           // 0..255
    const int n = r >> 7;
    const int h = xcd * 128 + (r & 127);
    const int cbase = hb * 512;
    const int w0 = cbase + 8 * t;

    // ms fragment: 8 ch x 8 px -> 4 chpair planes x 8 u32
    const float* msBase = ms + (size_t)n * CHW + h * WW + w0;
    uint msq[4][8];
#pragma unroll
    for (int cp = 0; cp < 4; ++cp) {
        float4 a0 = *(const float4*)(msBase + (2 * cp) * HWSZ);
        float4 a1 = *(const float4*)(msBase + (2 * cp) * HWSZ + 4);
        float4 b0 = *(const float4*)(msBase + (2 * cp + 1) * HWSZ);
        float4 b1 = *(const float4*)(msBase + (2 * cp + 1) * HWSZ + 4);
        msq[cp][0] = pknorm(a0.x, b0.x); msq[cp][1] = pknorm(a0.y, b0.y);
        msq[cp][2] = pknorm(a0.z, b0.z); msq[cp][3] = pknorm(a0.w, b0.w);
        msq[cp][4] = pknorm(a1.x, b1.x); msq[cp][5] = pknorm(a1.y, b1.y);
        msq[cp][6] = pknorm(a1.z, b1.z); msq[cp][7] = pknorm(a1.w, b1.w);
    }

    // halo: 2 u32/lane. id = 2t+e: cp = id>>5, k = id&31,
    // local old u32 u = k<16 ? k : 512+k; image col j = reflect(cbase+u-16)
    int eCp[2], eJ[2], eLds[2], eQpos[2];
#pragma unroll
    for (int e = 0; e < 2; ++e) {
        int id = 2 * t + e;
        eCp[e] = id >> 5;
        int k = id & 31;
        int u = (k < 16) ? k : (512 + k);
        int j = cbase + u - 16;
        if (j < 0) j = -j;
        if (j > WW - 1) j = 2 * (WW - 1) - j;
        eJ[e] = j;
        int go = u >> 2;
        int sl = (go & 1) ? (68 + (go >> 1)) : (go >> 1);
        eLds[e] = eCp[e] * 544 + sl * 4 + (u & 3);
        int gg = j >> 2;
        int sg = (gg & 1) ? (128 + (gg >> 1)) : (gg >> 1);
        eQpos[e] = sg * 4 + (j & 3);
    }

    uint minv[8];
#pragma unroll
    for (int p = 0; p < 8; ++p) minv[p] = 0xffffffffu;

    const float* tgtN = tgt + (size_t)n * CHW;
    const uint* qtN = qt + ((size_t)n * 4 << 20); // n*4 planes of 1M u32

    uint hr[2][2]; // halo regs, by di parity

    if (USE_QT) {
        // prologue: stage di=0 into buf0
        int gr0 = reflect_idx(h - 16);
#pragma unroll
        for (int e = 0; e < 2; ++e)
            hr[0][e] = qtN[((size_t)(eCp[e] << 10) + gr0) * 1024 + eQpos[e]];
#pragma unroll
        for (int cp = 0; cp < 4; ++cp) {
            const uint* qr = qtN + ((size_t)(cp << 10) + gr0) * 1024;
            GLD16(qr + 256 * hb + 4 * t, &ldsU[0][cp * 544 + 8]);
            GLD16(qr + 512 + 256 * hb + 4 * t, &ldsU[0][cp * 544 + 280]);
        }
    }

    for (int di = 0; di < 9; ++di) {
        const int buf = di & 1;
        if (USE_QT) {
            if (di < 8) {
                int gr = reflect_idx(h + (di - 3) * 4);
#pragma unroll
                for (int e = 0; e < 2; ++e)
                    hr[buf ^ 1][e] = qtN[((size_t)(eCp[e] << 10) + gr) * 1024 + eQpos[e]];
#pragma unroll
                for (int cp = 0; cp < 4; ++cp) {
                    const uint* qr = qtN + ((size_t)(cp << 10) + gr) * 1024;
                    GLD16(qr + 256 * hb + 4 * t, &ldsU[buf ^ 1][cp * 544 + 8]);
                    GLD16(qr + 512 + 256 * hb + 4 * t, &ldsU[buf ^ 1][cp * 544 + 280]);
                }
                asm volatile("s_waitcnt vmcnt(10)" ::: "memory");
            } else {
                asm volatile("s_waitcnt vmcnt(0)" ::: "memory");
            }
            ldsU[buf][eLds[0]] = hr[buf][0];
            ldsU[buf][eLds[1]] = hr[buf][1];
        } else {
            // synchronous staging from f32 tgt (fallback)
            int gr = reflect_idx(h + (di - 4) * 4);
            const float* rb = tgtN + (size_t)gr * WW + w0;
#pragma unroll
            for (int cp = 0; cp < 4; ++cp) {
                float4 a0 = *(const float4*)(rb + (2 * cp) * HWSZ);
                float4 a1 = *(const float4*)(rb + (2 * cp) * HWSZ + 4);
                float4 b0 = *(const float4*)(rb + (2 * cp + 1) * HWSZ);
                float4 b1 = *(const float4*)(rb + (2 * cp + 1) * HWSZ + 4);
                uint4 u0, u1;
                u0.x = pknorm(a0.x, b0.x); u0.y = pknorm(a0.y, b0.y);
                u0.z = pknorm(a0.z, b0.z); u0.w = pknorm(a0.w, b0.w);
                u1.x = pknorm(a1.x, b1.x); u1.y = pknorm(a1.y, b1.y);
                u1.z = pknorm(a1.z, b1.z); u1.w = pknorm(a1.w, b1.w);
                *(uint4*)&ldsU[0][cp * 544 + (t + 2) * 4] = u0;      // even granule
                *(uint4*)&ldsU[0][cp * 544 + 280 + 4 * t] = u1;      // odd granule
            }
#pragma unroll
            for (int e = 0; e < 2; ++e) {
                const float* p0 = tgtN + (size_t)(2 * eCp[e]) * HWSZ + (size_t)gr * WW + eJ[e];
                ldsU[0][eLds[e]] = pknorm(p0[0], p0[HWSZ]);
            }
        }

        const uint* lbuf = USE_QT ? &ldsU[buf][0] : &ldsU[0][0];
        // sliding E/O windows, stride-1 slot reads (conflict-free)
        uint4 winE[4], winO[4];
#pragma unroll
        for (int cp = 0; cp < 4; ++cp) {
            winE[cp] = *(const uint4*)(lbuf + cp * 544 + 4 * t);
            winO[cp] = *(const uint4*)(lbuf + cp * 544 + 272 + 4 * t);
        }
#pragma unroll
        for (int dj = 0; dj < 9; ++dj) {
            uint acc[8] = {0, 0, 0, 0, 0, 0, 0, 0};
#pragma unroll
            for (int cp = 0; cp < 4; ++cp) {
                uint4 lo = (dj & 1) ? winO[cp] : winE[cp];
                uint4 hi = (dj & 1) ? winE[cp] : winO[cp];
                acc[0] = sadu16(msq[cp][0], lo.x, acc[0]);
                acc[1] = sadu16(msq[cp][1], lo.y, acc[1]);
                acc[2] = sadu16(msq[cp][2], lo.z, acc[2]);
                acc[3] = sadu16(msq[cp][3], lo.w, acc[3]);
                acc[4] = sadu16(msq[cp][4], hi.x, acc[4]);
                acc[5] = sadu16(msq[cp][5], hi.y, acc[5]);
                acc[6] = sadu16(msq[cp][6], hi.z, acc[6]);
                acc[7] = sadu16(msq[cp][7], hi.w, acc[7]);
            }
#pragma unroll
            for (int p = 0; p < 8; ++p) minv[p] = min(minv[p], acc[p]);
            if (dj < 8) {
                int m = dj >> 1;
                if ((dj & 1) == 0) {
#pragma unroll
                    for (int cp = 0; cp < 4; ++cp)
                        winE[cp] = *(const uint4*)(lbuf + cp * 544 + 4 * (t + m + 1));
                } else {
#pragma unroll
                    for (int cp = 0; cp < 4; ++cp)
                        winO[cp] = *(const uint4*)(lbuf + cp * 544 + 272 + 4 * (t + m + 1));
                }
            }
        }
    }

    // ---- epilogue (single wave) ----
    float lmin = 1.0e38f, lmax = -1.0e38f;
#pragma unroll
    for (int k = 0; k < 8; ++k) {
        float4 v = ((const float4*)wsF)[k * 64 + t];
        float4 w = ((const float4*)(wsF + 2048))[k * 64 + t];
        lmin = fminf(lmin, fminf(fminf(v.x, v.y), fminf(v.z, v.w)));
        lmax = fmaxf(lmax, fmaxf(fmaxf(w.x, w.y), fmaxf(w.z, w.w)));
    }
#pragma unroll
    for (int off = 32; off > 0; off >>= 1) {
        lmin = fminf(lmin, __shfl_xor(lmin, off));
        lmax = fmaxf(lmax, __shfl_xor(lmax, off));
    }
    float thresh = lmin + (lmax - lmin) * (10.0f / 255.0f);

    const float* dp = wsF + WS_DIFF + (size_t)n * HWSZ + h * WW + w0;
    float4 da = *(const float4*)dp;
    float4 db = *(const float4*)(dp + 4);
    float dv[8] = {da.x, da.y, da.z, da.w, db.x, db.y, db.z, db.w};

    const float inv = 1.0f / 65535.0f;
    float lsum = 0.f, lcnt = 0.f;
#pragma unroll
    for (int p = 0; p < 8; ++p) {
        if (dv[p] > thresh) { lsum += (float)minv[p] * inv; lcnt += 1.f; }
    }
#pragma unroll
    for (int off = 32; off > 0; off >>= 1) {
        lsum += __shfl_down(lsum, off);
        lcnt += __shfl_down(lcnt, off);
    }
    if (t == 0) {
        atomicAdd(&wsF[WS_SUM], lsum);
        atomicAdd(&wsF[WS_CNT], lcnt);
        __threadfence();
        unsigned tk = atomicAdd((unsigned*)&wsF[WS_TKT], 1u);
        if (tk == NBLK_MAIN - 1) {
            float s = atomicAdd(&wsF[WS_SUM], 0.f);
            float c = atomicAdd(&wsF[WS_CNT], 0.f);
            out[0] = (c > 0.f) ? (s / fmaxf(c, 1.f)) : 0.f;
        }
    }
}

extern "C" void kernel_launch(void* const* d_in, const int* in_sizes, int n_in,
                              void* d_out, int out_size, void* d_ws, size_t ws_size,
                              hipStream_t stream) {
    const float* ms  = (const float*)d_in[0];
    const float* tgt = (const float*)d_in[1];
    const float* msO = (const float*)d_in[2];
    const float* pan = (const float*)d_in[3];
    float* out = (float*)d_out;
    float* wsF = (float*)d_ws;
    uint* qt = (uint*)d_ws + WS_QT;

    const size_t needQt = ((size_t)WS_QT + (size_t)NIMG * 4 * HWSZ) * 4u;
    const bool useQt = ws_size >= needQt;

    if (useQt) {
        k_quant<<<NIMG * 4 * 1024, 256, 0, stream>>>(tgt, qt);
        k_mask<<<NBLK_MASK, 256, 0, stream>>>(msO, pan, wsF, wsF + WS_DIFF);
        k_main<true><<<NBLK_MAIN, 64, 0, stream>>>(ms, tgt, qt, wsF, out);
    } else {
        k_mask<<<NBLK_MASK, 256, 0, stream>>>(msO, pan, wsF, wsF + WS_DIFF);
        k_main<false><<<NBLK_MAIN, 64, 0, stream>>>(ms, tgt, qt, wsF, out);
    }
}